// Round 9
// baseline (250.126 us; speedup 1.0000x reference)
//
#include <hip/hip_runtime.h>
#include <hip/hip_fp16.h>
#include <math.h>

#define N_NODES 100000
#define N_EDGES 1600000
#define IN_DIM 128
#define F_DIM 128      // HEADS*OUT_DIM
#define NEG_SLOPE 0.2f

#define BUCKW_LOG 7            // 128 nodes per bucket
#define NBUCK 784              // covers 100352 >= N_NODES
#define NBLK_S 100             // bscat blocks (run FIRST in the mega grid)
#define EPSB 16000             // edges per bscat block (NBLK_S*EPSB == N_EDGES)
#define SLAB_CAP 64            // ebuf slots per (bucket,block) slab (mean 20.4, +9.7 sigma)
#define GB 1563                // gemm blocks: ceil(100000/64)
#define PADBIT 0x80000000u

typedef short v8s __attribute__((ext_vector_type(8)));
typedef float v4f __attribute__((ext_vector_type(4)));

static __device__ __forceinline__ unsigned short f2bf(float f) {
    unsigned u = __float_as_uint(f);
    u += 0x7fffu + ((u >> 16) & 1u);
    return (unsigned short)(u >> 16);
}
static __device__ __forceinline__ float lo2f(unsigned u) { return __uint_as_float(u << 16); }
static __device__ __forceinline__ float hi2f(unsigned u) { return __uint_as_float(u & 0xffff0000u); }

// ---------------- init: W transpose/convert ----------------------------------
__global__ __launch_bounds__(1024) void k_init(const float* __restrict__ W,
                                               unsigned short* __restrict__ Wt) {
    int i = blockIdx.x * 1024 + threadIdx.x;   // 16384 elems
    int n = i >> 7, k = i & 127;
    Wt[n * 128 + k] = f2bf(W[k * 128 + n]);
}

// ---------------- MEGA: bscat (blocks < NBLK_S, FIRST) + GEMM tiles ----------
// GEMM: B-fragments read DIRECTLY from global Wt (L1/L2-hot 32KB shared by all
// blocks) — dropping the Bs LDS stage cuts LDS 53->18.4KB, raising occupancy
// 3->8 blocks/CU on a kernel R7 measured latency-bound (Occ 13%, VALU 5%).
// bscat: 8 independent edge chains/thread for MLP; block-private LDS cursors.
__global__ __launch_bounds__(256) void k_mega(const float* __restrict__ x,
                                              const unsigned short* __restrict__ Wt,
                                              unsigned short* __restrict__ h16,
                                              const float* __restrict__ att_src,
                                              const float* __restrict__ att_dst,
                                              float* __restrict__ a_src,
                                              float* __restrict__ a_dst,
                                              const int* __restrict__ ei,
                                              int* __restrict__ pcnt,
                                              int* __restrict__ ebuf) {
    __shared__ unsigned short As[64][136];    // [row][k]  (aliased by bscat cursors)
    __shared__ float attl[256];               // [0..127]=att_src, [128..255]=att_dst
    const int t = threadIdx.x;

    if (blockIdx.x < NBLK_S) {            // ---- bscat part (runs first) ----
        int blk = blockIdx.x;
        int* cur = (int*)&As[0][0];       // 784 ints, block-private
        for (int i = t; i < NBUCK; i += 256) cur[i] = 0;
        __syncthreads();
        const int4* ps = (const int4*)(ei + blk * EPSB);
        const int4* pd = (const int4*)(ei + N_EDGES + blk * EPSB);
        #define PLACE(SV, DV) {                                                \
            int b_ = (DV) >> BUCKW_LOG;                                        \
            int r_ = atomicAdd(&cur[b_], 1);                                   \
            ebuf[((b_ * NBLK_S + blk) << 6) + r_] = (SV) | (((DV) & 127) << 17); \
        }
        for (int i = t; i < EPSB / 8; i += 256) {   // 8 edges in flight
            int4 s0 = ps[2 * i], s1 = ps[2 * i + 1];
            int4 d0 = pd[2 * i], d1 = pd[2 * i + 1];
            PLACE(s0.x, d0.x); PLACE(s0.y, d0.y);
            PLACE(s0.z, d0.z); PLACE(s0.w, d0.w);
            PLACE(s1.x, d1.x); PLACE(s1.y, d1.y);
            PLACE(s1.z, d1.z); PLACE(s1.w, d1.w);
        }
        #undef PLACE
        __syncthreads();
        for (int b = t; b < NBUCK; b += 256) pcnt[b * NBLK_S + blk] = cur[b];
        return;
    }

    const int n0 = (blockIdx.x - NBLK_S) * 64;
    attl[t] = (t < 128) ? att_src[t] : att_dst[t - 128];

    {
        int row = t >> 2, k0 = (t & 3) * 32;
        int n = n0 + row;
        #pragma unroll
        for (int i = 0; i < 4; i++) {
            float4 va = make_float4(0.f,0.f,0.f,0.f), vb = va;
            if (n < N_NODES) {
                const float* p = x + (size_t)n * IN_DIM + k0 + i * 8;
                va = *(const float4*)p;
                vb = *(const float4*)(p + 4);
            }
            uint4 u;
            u.x = f2bf(va.x) | ((unsigned)f2bf(va.y) << 16);
            u.y = f2bf(va.z) | ((unsigned)f2bf(va.w) << 16);
            u.z = f2bf(vb.x) | ((unsigned)f2bf(vb.y) << 16);
            u.w = f2bf(vb.z) | ((unsigned)f2bf(vb.w) << 16);
            *(uint4*)&As[row][k0 + i * 8] = u;
        }
    }
    __syncthreads();

    const int w = t >> 6, lane = t & 63;
    const int mr = lane & 15, quad = lane >> 4;
    const int m0 = w * 16;

    v4f acc[8];
    #pragma unroll
    for (int nt = 0; nt < 8; nt++) acc[nt] = (v4f){0.f, 0.f, 0.f, 0.f};

    #pragma unroll
    for (int kk = 0; kk < 4; kk++) {
        int kof = kk * 32 + quad * 8;
        v8s a = *(const v8s*)&As[m0 + mr][kof];
        #pragma unroll
        for (int nt = 0; nt < 8; nt++) {
            v8s b = *(const v8s*)(Wt + (nt * 16 + mr) * IN_DIM + kof);
            acc[nt] = __builtin_amdgcn_mfma_f32_16x16x32_bf16(a, b, acc[nt], 0, 0, 0);
        }
    }

    __syncthreads();
    #pragma unroll
    for (int nt = 0; nt < 8; nt++)
        #pragma unroll
        for (int r = 0; r < 4; r++)
            As[m0 + quad * 4 + r][nt * 16 + mr] = f2bf(acc[nt][r]);
    __syncthreads();
    {
        int row = m0 + (lane >> 2);
        int c0  = (lane & 3) * 32;        // 32 cols = one head
        int n = n0 + row;
        if (n < N_NODES) {
            float ds = 0.f, dd = 0.f;
            #pragma unroll
            for (int i = 0; i < 4; i++) {
                uint4 v = *(const uint4*)&As[row][c0 + i * 8];
                *(uint4*)&h16[(size_t)n * F_DIM + c0 + i * 8] = v;
                float f0 = lo2f(v.x), f1 = hi2f(v.x);
                float f2 = lo2f(v.y), f3 = hi2f(v.y);
                float f4 = lo2f(v.z), f5 = hi2f(v.z);
                float f6 = lo2f(v.w), f7 = hi2f(v.w);
                const float* ps = &attl[c0 + i * 8];
                const float* pd = &attl[128 + c0 + i * 8];
                ds += f0*ps[0] + f1*ps[1] + f2*ps[2] + f3*ps[3]
                    + f4*ps[4] + f5*ps[5] + f6*ps[6] + f7*ps[7];
                dd += f0*pd[0] + f1*pd[1] + f2*pd[2] + f3*pd[3]
                    + f4*pd[4] + f5*pd[5] + f6*pd[6] + f7*pd[7];
            }
            int hd = lane & 3;
            a_src[n * 4 + hd] = ds;
            a_dst[n * 4 + hd] = dd;
        }
    }
}

// ---------------- agg2: one block per bucket (R8-proven, 99us) ---------------
// Phase 1: coalesced read of the bucket's contiguous 25.6KB slab window ->
// per-node LDS lists via LDS cursors. Phase 2: 16 waves x 8 nodes, gather loop
// with LDS indices.
__global__ __launch_bounds__(1024) void k_agg2(const uint4* __restrict__ h16x4,
                                               const float* __restrict__ a_src,
                                               const float* __restrict__ a_dst,
                                               const int* __restrict__ pcnt,
                                               const int* __restrict__ ebuf,
                                               const float* __restrict__ bias,
                                               float* __restrict__ out) {
    __shared__ int list[128 << 6];     // 128 nodes x 64 slots = 32KB
    __shared__ int cnt[128];
    __shared__ int scnt[NBLK_S];
    const int b = blockIdx.x, t = threadIdx.x;

    if (t < NBLK_S) scnt[t] = pcnt[b * NBLK_S + t];
    if (t < 128) cnt[t] = 0;
    __syncthreads();
    {   // build: 1600 int4 over 1024 threads
        const int4* win = (const int4*)(ebuf + (size_t)b * (NBLK_S * SLAB_CAP));
        #pragma unroll
        for (int it = 0; it < 2; it++) {
            int i4 = it * 1024 + t;
            if (i4 < NBLK_S * SLAB_CAP / 4) {
                int4 e4 = win[i4];
                int base = i4 << 2;
                int es0 = e4.x, es1 = e4.y, es2 = e4.z, es3 = e4.w;
                #define PUT(J, E) {                                            \
                    int idx = base + (J);                                      \
                    if ((idx & 63) < scnt[idx >> 6]) {                         \
                        int dl = ((E) >> 17) & 127;                            \
                        int r = atomicAdd(&cnt[dl], 1);                        \
                        list[(dl << 6) + r] = (E) & 0x1ffff;                   \
                    }                                                          \
                }
                PUT(0, es0); PUT(1, es1); PUT(2, es2); PUT(3, es3);
                #undef PUT
            }
        }
    }
    __syncthreads();
    if (t < 128) {                     // pad each list to multiple of 4
        int c = cnt[t], cp = (c + 3) & ~3;
        for (int k = c; k < cp; k++) list[(t << 6) + k] = (int)PADBIT;
    }
    __syncthreads();

    const int wv = t >> 6, lane = t & 63;
    const int grp = lane >> 4, g = lane & 15, hd = g >> 2;
    const float4 bb0 = *(const float4*)&bias[g * 8];
    const float4 bb1 = *(const float4*)&bias[g * 8 + 4];

    for (int k8 = 0; k8 < 8; k8++) {
        int nl = (wv << 3) + k8;       // wave wv owns nodes [8wv, 8wv+8)
        int n = (b << BUCKW_LOG) + nl;
        if (n >= N_NODES) break;

        float adn = a_dst[n * 4 + hd];
        float p0 = 0.f;
        if (grp == 0) {
            float e0 = a_src[n * 4 + hd] + adn;
            e0 = e0 > 0.f ? e0 : NEG_SLOPE * e0;
            p0 = __expf(e0);           // self-loop (group 0 only)
        }
        uint4 hs = h16x4[(size_t)n * 16 + g];
        float l  = p0;
        float a0 = p0 * lo2f(hs.x), a1 = p0 * hi2f(hs.x);
        float a2 = p0 * lo2f(hs.y), a3 = p0 * hi2f(hs.y);
        float a4 = p0 * lo2f(hs.z), a5 = p0 * hi2f(hs.z);
        float a6 = p0 * lo2f(hs.w), a7 = p0 * hi2f(hs.w);

        int cn = cnt[nl];
        const int* sp = &list[(nl << 6) + grp];
        int steps = (cn + 3) >> 2;
        int tt = 0;
        for (; tt + 2 <= steps; tt += 2) {
            int u0 = sp[4 * tt];
            int u1 = sp[4 * tt + 4];
            int s0 = u0 & 0x7fffffff;
            int s1 = u1 & 0x7fffffff;
            float as0 = a_src[s0 * 4 + hd];
            float as1 = a_src[s1 * 4 + hd];
            uint4 h0 = h16x4[(size_t)s0 * 16 + g];
            uint4 h1 = h16x4[(size_t)s1 * 16 + g];
            float w0 = as0 + adn; w0 = w0 > 0.f ? w0 : NEG_SLOPE * w0;
            float w1 = as1 + adn; w1 = w1 > 0.f ? w1 : NEG_SLOPE * w1;
            float q0 = __expf(w0);
            float q1 = __expf(w1);
            q0 = u0 < 0 ? 0.f : q0;    // pad slot -> zero weight
            q1 = u1 < 0 ? 0.f : q1;
            l  += q0 + q1;
            a0 += q0 * lo2f(h0.x) + q1 * lo2f(h1.x);
            a1 += q0 * hi2f(h0.x) + q1 * hi2f(h1.x);
            a2 += q0 * lo2f(h0.y) + q1 * lo2f(h1.y);
            a3 += q0 * hi2f(h0.y) + q1 * hi2f(h1.y);
            a4 += q0 * lo2f(h0.z) + q1 * lo2f(h1.z);
            a5 += q0 * hi2f(h0.z) + q1 * hi2f(h1.z);
            a6 += q0 * lo2f(h0.w) + q1 * lo2f(h1.w);
            a7 += q0 * hi2f(h0.w) + q1 * hi2f(h1.w);
        }
        if (tt < steps) {
            int u0 = sp[4 * tt];
            int s0 = u0 & 0x7fffffff;
            float as0 = a_src[s0 * 4 + hd];
            uint4 h0 = h16x4[(size_t)s0 * 16 + g];
            float w0 = as0 + adn; w0 = w0 > 0.f ? w0 : NEG_SLOPE * w0;
            float q0 = __expf(w0);
            q0 = u0 < 0 ? 0.f : q0;
            l  += q0;
            a0 += q0 * lo2f(h0.x);
            a1 += q0 * hi2f(h0.x);
            a2 += q0 * lo2f(h0.y);
            a3 += q0 * hi2f(h0.y);
            a4 += q0 * lo2f(h0.z);
            a5 += q0 * hi2f(h0.z);
            a6 += q0 * lo2f(h0.w);
            a7 += q0 * hi2f(h0.w);
        }
        #define RED2(v) v += __shfl_xor(v, 16, 64); v += __shfl_xor(v, 32, 64);
        RED2(l); RED2(a0); RED2(a1); RED2(a2); RED2(a3);
        RED2(a4); RED2(a5); RED2(a6); RED2(a7);
        #undef RED2

        if (grp == 0) {
            float inv = 1.f / (l + 1e-16f);
            float o0 = a0 * inv + bb0.x, o1 = a1 * inv + bb0.y;
            float o2 = a2 * inv + bb0.z, o3 = a3 * inv + bb0.w;
            float o4 = a4 * inv + bb1.x, o5 = a5 * inv + bb1.y;
            float o6 = a6 * inv + bb1.z, o7 = a7 * inv + bb1.w;
            o0 = o0 > 0.f ? o0 : __expf(o0) - 1.f;
            o1 = o1 > 0.f ? o1 : __expf(o1) - 1.f;
            o2 = o2 > 0.f ? o2 : __expf(o2) - 1.f;
            o3 = o3 > 0.f ? o3 : __expf(o3) - 1.f;
            o4 = o4 > 0.f ? o4 : __expf(o4) - 1.f;
            o5 = o5 > 0.f ? o5 : __expf(o5) - 1.f;
            o6 = o6 > 0.f ? o6 : __expf(o6) - 1.f;
            o7 = o7 > 0.f ? o7 : __expf(o7) - 1.f;
            *(float4*)&out[(size_t)n * F_DIM + g * 8]     = make_float4(o0, o1, o2, o3);
            *(float4*)&out[(size_t)n * F_DIM + g * 8 + 4] = make_float4(o4, o5, o6, o7);
        }
    }
}

extern "C" void kernel_launch(void* const* d_in, const int* in_sizes, int n_in,
                              void* d_out, int out_size, void* d_ws, size_t ws_size,
                              hipStream_t stream) {
    const float* x       = (const float*)d_in[0];
    const int*   ei      = (const int*)d_in[1];   // (2, E) row-major int32
    const float* W       = (const float*)d_in[2];
    const float* att_src = (const float*)d_in[3];
    const float* att_dst = (const float*)d_in[4];
    const float* bias    = (const float*)d_in[5];
    float*       out     = (float*)d_out;

    char* ws = (char*)d_ws;
    unsigned short* h16 = (unsigned short*)ws; ws += (size_t)N_NODES * F_DIM * 2;   // 25.6 MB
    unsigned short* Wt  = (unsigned short*)ws; ws += (size_t)IN_DIM * F_DIM * 2;    // 32 KB
    float* a_src  = (float*)ws; ws += (size_t)N_NODES * 4 * 4;                      // 1.6 MB
    float* a_dst  = (float*)ws; ws += (size_t)N_NODES * 4 * 4;                      // 1.6 MB
    int*   pcnt   = (int*)ws;   ws += (size_t)NBUCK * NBLK_S * 4;                   // 0.31 MB
    int*   ebuf   = (int*)ws;   ws += (size_t)NBUCK * NBLK_S * SLAB_CAP * 4;        // 20.1 MB

    k_init<<<16, 1024, 0, stream>>>(W, Wt);
    k_mega<<<GB + NBLK_S, 256, 0, stream>>>(x, Wt, h16, att_src, att_dst,
                                            a_src, a_dst, ei, pcnt, ebuf);
    k_agg2<<<NBUCK, 1024, 0, stream>>>((const uint4*)h16, a_src, a_dst,
                                       pcnt, ebuf, bias, out);
}